// Round 1
// baseline (2284.798 us; speedup 1.0000x reference)
//
#include <hip/hip_runtime.h>
#include <math.h>

#define BB 256
#define TT 2048
#define HH 64

__device__ __forceinline__ float tanh_fast(float v) {
    // tanh(x) = 1 - 2/(e^{2x}+1); saturates correctly at +/-inf
    float e = __expf(2.0f * v);
    return 1.0f - 2.0f / (e + 1.0f);
}

__device__ __forceinline__ float rl(float v, int lane) {
    return __int_as_float(__builtin_amdgcn_readlane(__float_as_int(v), lane));
}

__global__ __launch_bounds__(256, 1)
void pgjanet_kernel(const float* __restrict__ x,
                    const float* __restrict__ h0,
                    const float* __restrict__ Wa,  const float* __restrict__ ba,
                    const float* __restrict__ Wp1, const float* __restrict__ bp1,
                    const float* __restrict__ Wp2, const float* __restrict__ bp2,
                    const float* __restrict__ Wf,  const float* __restrict__ bf,
                    const float* __restrict__ Wg,  const float* __restrict__ bg,
                    const float* __restrict__ Wo,  const float* __restrict__ bo,
                    float* __restrict__ out)
{
    const int b   = blockIdx.x;
    const int tid = threadIdx.x;
    const int j   = tid & 63;                                   // hidden index (lane)
    const int w   = __builtin_amdgcn_readfirstlane(tid >> 6);   // wave id 0..3 (uniform)
    const int kb  = w * 16;                                     // this wave's k-range base

    // partial-sum exchange buffers: part1[gate][wave][j], part2[gate][wave][j]
    __shared__ float part1[3][4][HH];
    __shared__ float part2[2][4][HH];

    // ---- preload weights into VGPRs (this wave's k-slice of each matrix) ----
    float wa[16], wp1[16], wp2[16], wfh[16], wfu[16], wgh[16], wgu[16];
#pragma unroll
    for (int i = 0; i < 16; ++i) {
        wa[i]  = Wa [j * (HH + 1) + kb + i];
        wp1[i] = Wp1[j * (HH + 1) + kb + i];
        wp2[i] = Wp2[j * (HH + 1) + kb + i];
        wfh[i] = Wf [j * (2 * HH) + kb + i];
        wfu[i] = Wf [j * (2 * HH) + HH + kb + i];
        wgh[i] = Wg [j * (2 * HH) + kb + i];
        wgu[i] = Wg [j * (2 * HH) + HH + kb + i];
    }
    const float waH  = Wa [j * (HH + 1) + HH];   // extra-column weights
    const float wp1H = Wp1[j * (HH + 1) + HH];
    const float wp2H = Wp2[j * (HH + 1) + HH];
    const float ba_r = ba[j], bp1_r = bp1[j], bp2_r = bp2[j];
    const float bf_r = bf[j], bg_r = bg[j];
    const float wo0 = Wo[j], wo1 = Wo[HH + j];
    const float bo0 = bo[0], bo1 = bo[1];

    float h = h0[b * HH + j];   // lane j holds h[j]; identical in all 4 waves

    const float* xp = x   + (size_t)b * (TT * 2);
    float*       yp = out + (size_t)b * (TT * 2);

    // software-pipelined x load (used ~mid-iteration next step)
    float xi = xp[0], xq = xp[1];

    for (int t = 0; t < TT; ++t) {
        const int tn = (t + 1 < TT) ? (t + 1) : (TT - 1);
        float xi_n = xp[2 * tn];
        float xq_n = xp[2 * tn + 1];

        // broadcast h[kb..kb+15] to SGPRs
        float sh[16];
#pragma unroll
        for (int i = 0; i < 16; ++i) sh[i] = rl(h, kb + i);

        // phase 1 partials: a, p1, p2 (h-part only; extra column added at combine)
        float acc_a = 0.f, acc_1 = 0.f, acc_2 = 0.f;
#pragma unroll
        for (int i = 0; i < 16; ++i) {
            acc_a = fmaf(sh[i], wa[i],  acc_a);
            acc_1 = fmaf(sh[i], wp1[i], acc_1);
            acc_2 = fmaf(sh[i], wp2[i], acc_2);
        }
        part1[0][w][j] = acc_a;
        part1[1][w][j] = acc_1;
        part1[2][w][j] = acc_2;

        // x-derived scalars (wave-uniform values in VGPRs)
        float amp  = sqrtf(xi * xi + xq * xq);
        float inv  = (amp > 0.f) ? (1.0f / amp) : 0.0f;
        float ct   = (amp > 0.f) ? (xi * inv) : 1.0f;   // cos(atan2(q,i)) ; atan2(0,0)=0 -> cos=1
        float st   = xq * inv;                          // sin(atan2(q,i)) ; 0 when amp==0

        __syncthreads();   // barrier 1

        // combine partials (all waves, redundantly)
        float pre_a = part1[0][0][j] + part1[0][1][j] + part1[0][2][j] + part1[0][3][j];
        float pre_1 = part1[1][0][j] + part1[1][1][j] + part1[1][2][j] + part1[1][3][j];
        float pre_2 = part1[2][0][j] + part1[2][1][j] + part1[2][2][j] + part1[2][3][j];
        pre_a = pre_a + fmaf(amp, waH,  ba_r);
        pre_1 = pre_1 + fmaf(ct,  wp1H, bp1_r);
        pre_2 = pre_2 + fmaf(st,  wp2H, bp2_r);

        float a  = tanh_fast(pre_a);
        float p1 = tanh_fast(pre_1);
        float p2 = tanh_fast(pre_2);
        float u  = a * p1 * p2 * (1.f - a) * (1.f - p1) * (1.f - p2);

        // broadcast u[kb..kb+15]
        float su[16];
#pragma unroll
        for (int i = 0; i < 16; ++i) su[i] = rl(u, kb + i);

        // phase 2 partials: f, g over concat [h, u]
        float acc_f = 0.f, acc_g = 0.f;
#pragma unroll
        for (int i = 0; i < 16; ++i) {
            acc_f = fmaf(sh[i], wfh[i], acc_f);
            acc_f = fmaf(su[i], wfu[i], acc_f);
            acc_g = fmaf(sh[i], wgh[i], acc_g);
            acc_g = fmaf(su[i], wgu[i], acc_g);
        }
        part2[0][w][j] = acc_f;
        part2[1][w][j] = acc_g;

        __syncthreads();   // barrier 2

        float pre_f = part2[0][0][j] + part2[0][1][j] + part2[0][2][j] + part2[0][3][j] + bf_r;
        float pre_g = part2[1][0][j] + part2[1][1][j] + part2[1][2][j] + part2[1][3][j] + bg_r;
        float f = 1.0f / (1.0f + __expf(-pre_f));
        float g = tanh_fast(pre_g);
        h = fmaf(f, h - g, g);   // f*h + (1-f)*g

        // output y_t = h @ Wo.T + bo  (rotate the reducing wave for balance)
        if (w == (t & 3)) {
            float y0 = h * wo0;
            float y1 = h * wo1;
#pragma unroll
            for (int m = 32; m >= 1; m >>= 1) {
                y0 += __shfl_xor(y0, m, 64);
                y1 += __shfl_xor(y1, m, 64);
            }
            if (j == 0) {
                yp[2 * t]     = y0 + bo0;
                yp[2 * t + 1] = y1 + bo1;
            }
        }

        xi = xi_n; xq = xq_n;
    }
}

extern "C" void kernel_launch(void* const* d_in, const int* in_sizes, int n_in,
                              void* d_out, int out_size, void* d_ws, size_t ws_size,
                              hipStream_t stream) {
    const float* x   = (const float*)d_in[0];
    const float* h0  = (const float*)d_in[1];
    const float* Wa  = (const float*)d_in[2];
    const float* ba  = (const float*)d_in[3];
    const float* Wp1 = (const float*)d_in[4];
    const float* bp1 = (const float*)d_in[5];
    const float* Wp2 = (const float*)d_in[6];
    const float* bp2 = (const float*)d_in[7];
    const float* Wf  = (const float*)d_in[8];
    const float* bf  = (const float*)d_in[9];
    const float* Wg  = (const float*)d_in[10];
    const float* bg  = (const float*)d_in[11];
    const float* Wo  = (const float*)d_in[12];
    const float* bo  = (const float*)d_in[13];
    float* out = (float*)d_out;

    pgjanet_kernel<<<dim3(BB), dim3(256), 0, stream>>>(
        x, h0, Wa, ba, Wp1, bp1, Wp2, bp2, Wf, bf, Wg, bg, Wo, bo, out);
}